// Round 3
// baseline (1234.896 us; speedup 1.0000x reference)
//
#include <hip/hip_runtime.h>

#define DFEAT 128
#define GEMM_ROWS 64

// ---------- degree accumulation: deg[dst] += w ----------
__global__ __launch_bounds__(256) void deg_kernel(const int* __restrict__ dst,
                                                  const float* __restrict__ w,
                                                  float* __restrict__ deg, int E)
{
    int i = blockIdx.x * 256 + threadIdx.x;
    if (i < E) atomicAdd(&deg[dst[i]], w[i]);
}

// ---------- dinv = rsqrt(deg + 1) in place (both deg arrays contiguous) ----------
__global__ __launch_bounds__(256) void dinv_kernel(float* __restrict__ deg, int n2)
{
    int i = blockIdx.x * 256 + threadIdx.x;
    if (i < n2) deg[i] = rsqrtf(deg[i] + 1.0f);
}

// ---------- GEMM: xw = (a + l) @ W  (fp32, launched once per W) ----------
__global__ __launch_bounds__(256) void gemm_kernel(
    const float* __restrict__ A, const float* __restrict__ L,
    const float* __restrict__ W, float* __restrict__ out, int n)
{
    __shared__ float sW[128 * 128];       // [k][col], 64 KB
    __shared__ float sX[GEMM_ROWS * 132]; // [row][k], padded stride, 33.8 KB

    const int tid = threadIdx.x;

    { // stage W, float4 copies
        const float4* Wv = (const float4*)W;
        float4* sWv = (float4*)sW;
        for (int i = tid; i < 128 * 128 / 4; i += 256) sWv[i] = Wv[i];
    }

    const int row0 = blockIdx.x * GEMM_ROWS;
    for (int i = tid; i < GEMM_ROWS * 128 / 4; i += 256) {
        int r  = i >> 5;           // 32 float4 per row
        int c4 = (i & 31) * 4;
        float4 va = make_float4(0.f, 0.f, 0.f, 0.f), vl = va;
        if (row0 + r < n) {
            size_t off = (size_t)(row0 + r) * DFEAT + c4;
            va = *(const float4*)&A[off];
            vl = *(const float4*)&L[off];
        }
        *(float4*)&sX[r * 132 + c4] =
            make_float4(va.x + vl.x, va.y + vl.y, va.z + vl.z, va.w + vl.w);
    }
    __syncthreads();

    const int colg = tid & 31;   // cols colg*4 .. +3
    const int rowg = tid >> 5;   // rows rowg*8 .. +7

    float acc[8][4] = {};
    for (int k = 0; k < 128; k += 4) {
        float4 w0 = *(const float4*)&sW[(k + 0) * 128 + colg * 4];
        float4 w1 = *(const float4*)&sW[(k + 1) * 128 + colg * 4];
        float4 w2 = *(const float4*)&sW[(k + 2) * 128 + colg * 4];
        float4 w3 = *(const float4*)&sW[(k + 3) * 128 + colg * 4];
        #pragma unroll
        for (int r = 0; r < 8; ++r) {
            float4 x = *(const float4*)&sX[(rowg * 8 + r) * 132 + k];
            acc[r][0] += x.x * w0.x + x.y * w1.x + x.z * w2.x + x.w * w3.x;
            acc[r][1] += x.x * w0.y + x.y * w1.y + x.z * w2.y + x.w * w3.y;
            acc[r][2] += x.x * w0.z + x.y * w1.z + x.z * w2.z + x.w * w3.z;
            acc[r][3] += x.x * w0.w + x.y * w1.w + x.z * w2.w + x.w * w3.w;
        }
    }

    #pragma unroll
    for (int r = 0; r < 8; ++r) {
        int row = row0 + rowg * 8 + r;
        if (row < n)
            *(float4*)&out[(size_t)row * DFEAT + colg * 4] =
                make_float4(acc[r][0], acc[r][1], acc[r][2], acc[r][3]);
    }
}

// ---------- edge scatter: agg[dst] += dinv[src]*w*dinv[dst] * xw[src] ----------
// One wave per edge; lane handles features 2*lane, 2*lane+1.
__global__ __launch_bounds__(256) void scatter_kernel(
    const int* __restrict__ src, const int* __restrict__ dst,
    const float* __restrict__ w, const float* __restrict__ dinv,
    const float* __restrict__ xw, float* __restrict__ agg, int E)
{
    const int lane = threadIdx.x & 63;
    int wid = blockIdx.x * 4 + (threadIdx.x >> 6);
    const int nw = gridDim.x * 4;
    for (int e = wid; e < E; e += nw) {
        int s = src[e];
        int t = dst[e];
        float norm = dinv[s] * w[e] * dinv[t];
        float2 v = *(const float2*)&xw[(size_t)s * DFEAT + 2 * lane];
        float* p = &agg[(size_t)t * DFEAT + 2 * lane];
        atomicAdd(p,     v.x * norm);
        atomicAdd(p + 1, v.y * norm);
    }
}

// ---------- agg += dinv^2 * xw  (local self-loop fold, before xw is overwritten) ----------
__global__ __launch_bounds__(256) void selfloop_kernel(
    const float* __restrict__ xw, const float* __restrict__ dinv,
    float* __restrict__ agg, int n)
{
    const int lane = threadIdx.x & 63;
    const int node = blockIdx.x * 4 + (threadIdx.x >> 6);
    if (node >= n) return;
    float d = dinv[node]; d *= d;
    size_t base = (size_t)node * DFEAT + 2 * lane;
    float2 x = *(const float2*)&xw[base];
    float2* p = (float2*)&agg[base];
    float2 v = *p;
    v.x += d * x.x;
    v.y += d * x.y;
    *p = v;
}

// ---------- fused epilogue (xw_g read from d_out, output written in place) ----------
__global__ __launch_bounds__(256) void final_kernel(
    const float* __restrict__ A, const float* __restrict__ Lr,
    const float* __restrict__ agg,
    const float* __restrict__ dinvg,
    const float* __restrict__ bl, const float* __restrict__ bg,
    float* __restrict__ io, int n)   // io: holds xw_g on entry, output on exit
{
    const int lane = threadIdx.x & 63;
    const int node = blockIdx.x * 4 + (threadIdx.x >> 6);
    if (node >= n) return;
    float dg = dinvg[node]; dg *= dg;
    size_t base = (size_t)node * DFEAT + 2 * lane;
    float2 a  = *(const float2*)&A[base];
    float2 l  = *(const float2*)&Lr[base];
    float2 xg = *(const float2*)&io[base];
    float2 b1 = *(const float2*)&bl[2 * lane];
    float2 b2 = *(const float2*)&bg[2 * lane];
    float2 ag = *(const float2*)&agg[base];

    float v0 = ag.x + dg * xg.x + b1.x + b2.x;
    float v1 = ag.y + dg * xg.y + b1.y + b2.y;
    float w0 = 1.0f / (1.0f + __expf(-v0));
    float w1 = 1.0f / (1.0f + __expf(-v1));
    float o0 = 2.0f * (a.x * w0 + l.x * (1.0f - w0));
    float o1 = 2.0f * (a.y * w1 + l.y * (1.0f - w1));
    *(float2*)&io[base] = make_float2(o0, o1);
}

extern "C" void kernel_launch(void* const* d_in, const int* in_sizes, int n_in,
                              void* d_out, int out_size, void* d_ws, size_t ws_size,
                              hipStream_t stream)
{
    const float* activity = (const float*)d_in[0];
    const float* learning = (const float*)d_in[1];
    const int*   ei  = (const int*)d_in[2];
    const float* ew  = (const float*)d_in[3];
    const int*   gei = (const int*)d_in[4];
    const float* gew = (const float*)d_in[5];
    const float* Wl  = (const float*)d_in[6];
    const float* bl  = (const float*)d_in[7];
    const float* Wg  = (const float*)d_in[8];
    const float* bg  = (const float*)d_in[9];

    const int n  = in_sizes[0] / DFEAT;   // 50000
    const int El = in_sizes[3];           // 500000
    const int Eg = in_sizes[5];           // 600000

    // ws layout (26.0 MB): [agg fp32 N*128][deg_l fp32 N][deg_g fp32 N]
    char* ws = (char*)d_ws;
    const size_t aggBytes = (size_t)n * DFEAT * sizeof(float);
    float* agg  = (float*)ws;
    float* degl = (float*)(ws + aggBytes);
    float* degg = degl + n;

    // xw buffer lives in d_out (exactly N*128 fp32)
    float* xw = (float*)d_out;

    hipMemsetAsync(d_ws, 0, aggBytes + 2 * (size_t)n * sizeof(float), stream);

    deg_kernel<<<dim3((El + 255) / 256), dim3(256), 0, stream>>>(ei + El, ew, degl, El);
    deg_kernel<<<dim3((Eg + 255) / 256), dim3(256), 0, stream>>>(gei + Eg, gew, degg, Eg);
    dinv_kernel<<<dim3((2 * n + 255) / 256), dim3(256), 0, stream>>>(degl, 2 * n);

    const int gemmGrid = (n + GEMM_ROWS - 1) / GEMM_ROWS;
    const int nodeGrid = (n + 3) / 4;

    // ---- local branch ----
    gemm_kernel<<<dim3(gemmGrid), dim3(256), 0, stream>>>(activity, learning, Wl, xw, n);
    scatter_kernel<<<dim3(4096), dim3(256), 0, stream>>>(ei, ei + El, ew, degl, xw, agg, El);
    selfloop_kernel<<<dim3(nodeGrid), dim3(256), 0, stream>>>(xw, degl, agg, n);

    // ---- global branch (reuses xw buffer in d_out) ----
    gemm_kernel<<<dim3(gemmGrid), dim3(256), 0, stream>>>(activity, learning, Wg, xw, n);
    scatter_kernel<<<dim3(4096), dim3(256), 0, stream>>>(gei, gei + Eg, gew, degg, xw, agg, Eg);

    // ---- fused epilogue: reads xw_g from d_out, writes output in place ----
    final_kernel<<<dim3(nodeGrid), dim3(256), 0, stream>>>(activity, learning, agg,
                                                           degg, bl, bg, xw, n);
}

// Round 4
// 544.221 us; speedup vs baseline: 2.2691x; 2.2691x over previous
//
#include <hip/hip_runtime.h>

#define DFEAT 128
#define GEMM_ROWS 64

// ---------- histogram: deg[base+dst] += w ; cnt[base+dst] += 1 ----------
__global__ __launch_bounds__(256) void hist_kernel(const int* __restrict__ dst,
                                                   const float* __restrict__ w,
                                                   float* __restrict__ deg,
                                                   int* __restrict__ cnt,
                                                   int base, int E)
{
    int e = blockIdx.x * 256 + threadIdx.x;
    if (e < E) {
        int t = dst[e];
        atomicAdd(&deg[base + t], w[e]);
        atomicAdd(&cnt[base + t], 1);
    }
}

// ---------- dinv = rsqrt(deg + 1) in place over 2N ----------
__global__ __launch_bounds__(256) void dinv_kernel(float* __restrict__ deg, int n2)
{
    int i = blockIdx.x * 256 + threadIdx.x;
    if (i < n2) deg[i] = rsqrtf(deg[i] + 1.0f);
}

// ---------- scan stage 1: per-block exclusive scan of cnt -> ptr, block total -> bsum ----------
__global__ __launch_bounds__(256) void scan1_kernel(const int* __restrict__ cnt,
                                                    int* __restrict__ ptr,
                                                    int* __restrict__ bsum, int n)
{
    __shared__ int tmp[256];
    int i = blockIdx.x * 256 + threadIdx.x;
    int v = (i < n) ? cnt[i] : 0;
    tmp[threadIdx.x] = v;
    __syncthreads();
    for (int off = 1; off < 256; off <<= 1) {
        int t = (threadIdx.x >= off) ? tmp[threadIdx.x - off] : 0;
        __syncthreads();
        tmp[threadIdx.x] += t;
        __syncthreads();
    }
    if (i < n) ptr[i] = tmp[threadIdx.x] - v;   // exclusive within block
    if (threadIdx.x == 255) bsum[blockIdx.x] = tmp[255];
}

// ---------- scan stage 2: single block exclusive scan of bsum (nb <= 512) ----------
__global__ __launch_bounds__(512) void scan2_kernel(int* __restrict__ bsum, int nb)
{
    __shared__ int tmp[512];
    int i = threadIdx.x;
    int v = (i < nb) ? bsum[i] : 0;
    tmp[i] = v;
    __syncthreads();
    for (int off = 1; off < 512; off <<= 1) {
        int t = (i >= off) ? tmp[i - off] : 0;
        __syncthreads();
        tmp[i] += t;
        __syncthreads();
    }
    if (i < nb) bsum[i] = tmp[i] - v;           // exclusive
}

// ---------- scan stage 3: add block offsets ----------
__global__ __launch_bounds__(256) void scan3_kernel(int* __restrict__ ptr,
                                                    const int* __restrict__ bsum, int n)
{
    int i = blockIdx.x * 256 + threadIdx.x;
    if (i < n) ptr[i] += bsum[blockIdx.x];
}

// ---------- position scatter: edata[pos] = (norm, src); destroys ptr into end-offsets ----------
__global__ __launch_bounds__(256) void pos_scatter_kernel(
    const int* __restrict__ src, const int* __restrict__ dst,
    const float* __restrict__ w, const float* __restrict__ dinv,
    int* __restrict__ ptr, int2* __restrict__ edata, int base, int E)
{
    int e = blockIdx.x * 256 + threadIdx.x;
    if (e >= E) return;
    int s = src[e], t = dst[e];
    float norm = dinv[base + s] * w[e] * dinv[base + t];
    int pos = atomicAdd(&ptr[base + t], 1);
    edata[pos] = make_int2(__float_as_int(norm), s);
}

// ---------- GEMM: xw = (a + l) @ W  (fp32, launched once per W) ----------
__global__ __launch_bounds__(256) void gemm_kernel(
    const float* __restrict__ A, const float* __restrict__ L,
    const float* __restrict__ W, float* __restrict__ out, int n)
{
    __shared__ float sW[128 * 128];
    __shared__ float sX[GEMM_ROWS * 132];

    const int tid = threadIdx.x;
    {
        const float4* Wv = (const float4*)W;
        float4* sWv = (float4*)sW;
        for (int i = tid; i < 128 * 128 / 4; i += 256) sWv[i] = Wv[i];
    }

    const int row0 = blockIdx.x * GEMM_ROWS;
    for (int i = tid; i < GEMM_ROWS * 128 / 4; i += 256) {
        int r  = i >> 5;
        int c4 = (i & 31) * 4;
        float4 va = make_float4(0.f, 0.f, 0.f, 0.f), vl = va;
        if (row0 + r < n) {
            size_t off = (size_t)(row0 + r) * DFEAT + c4;
            va = *(const float4*)&A[off];
            vl = *(const float4*)&L[off];
        }
        *(float4*)&sX[r * 132 + c4] =
            make_float4(va.x + vl.x, va.y + vl.y, va.z + vl.z, va.w + vl.w);
    }
    __syncthreads();

    const int colg = tid & 31;
    const int rowg = tid >> 5;

    float acc[8][4] = {};
    for (int k = 0; k < 128; k += 4) {
        float4 w0 = *(const float4*)&sW[(k + 0) * 128 + colg * 4];
        float4 w1 = *(const float4*)&sW[(k + 1) * 128 + colg * 4];
        float4 w2 = *(const float4*)&sW[(k + 2) * 128 + colg * 4];
        float4 w3 = *(const float4*)&sW[(k + 3) * 128 + colg * 4];
        #pragma unroll
        for (int r = 0; r < 8; ++r) {
            float4 x = *(const float4*)&sX[(rowg * 8 + r) * 132 + k];
            acc[r][0] += x.x * w0.x + x.y * w1.x + x.z * w2.x + x.w * w3.x;
            acc[r][1] += x.x * w0.y + x.y * w1.y + x.z * w2.y + x.w * w3.y;
            acc[r][2] += x.x * w0.z + x.y * w1.z + x.z * w2.z + x.w * w3.z;
            acc[r][3] += x.x * w0.w + x.y * w1.w + x.z * w2.w + x.w * w3.w;
        }
    }

    #pragma unroll
    for (int r = 0; r < 8; ++r) {
        int row = row0 + rowg * 8 + r;
        if (row < n)
            *(float4*)&out[(size_t)row * DFEAT + colg * 4] =
                make_float4(acc[r][0], acc[r][1], acc[r][2], acc[r][3]);
    }
}

// ---------- gather (local): agg[t] = sum_e norm*xw[src] + dinv^2*xw[t] ----------
__global__ __launch_bounds__(256) void gather_local_kernel(
    const float* __restrict__ xw, const int* __restrict__ ptr,
    const int2* __restrict__ edata, const float* __restrict__ dinv,
    float* __restrict__ agg, int n)
{
    const int lane = threadIdx.x & 63;
    const int node = blockIdx.x * 4 + (threadIdx.x >> 6);
    if (node >= n) return;
    int i0 = node ? ptr[node - 1] : 0;
    int i1 = ptr[node];
    float d = dinv[node]; d *= d;
    size_t base = (size_t)node * DFEAT + 2 * lane;
    float2 xs = *(const float2*)&xw[base];
    float2 acc = make_float2(d * xs.x, d * xs.y);
    for (int j = i0; j < i1; ++j) {
        int2 ed = edata[j];
        float nm = __int_as_float(ed.x);
        float2 v = *(const float2*)&xw[(size_t)ed.y * DFEAT + 2 * lane];
        acc.x += nm * v.x;
        acc.y += nm * v.y;
    }
    *(float2*)&agg[base] = acc;
}

// ---------- gather (global) + fused epilogue; result written into agg ----------
__global__ __launch_bounds__(256) void gather_global_kernel(
    const float* __restrict__ xw, const int* __restrict__ ptr,
    const int2* __restrict__ edata, const float* __restrict__ dinv,
    const float* __restrict__ A, const float* __restrict__ Lr,
    const float* __restrict__ bl, const float* __restrict__ bg,
    float* __restrict__ agg, int n)
{
    const int lane = threadIdx.x & 63;
    const int node = blockIdx.x * 4 + (threadIdx.x >> 6);
    if (node >= n) return;
    const int idx = n + node;                 // global segment index
    int i0 = ptr[idx - 1];                    // idx >= n >= 1, always valid
    int i1 = ptr[idx];
    float d = dinv[idx]; d *= d;
    size_t base = (size_t)node * DFEAT + 2 * lane;
    float2 xs = *(const float2*)&xw[base];
    float2 acc = make_float2(d * xs.x, d * xs.y);
    for (int j = i0; j < i1; ++j) {
        int2 ed = edata[j];
        float nm = __int_as_float(ed.x);
        float2 v = *(const float2*)&xw[(size_t)ed.y * DFEAT + 2 * lane];
        acc.x += nm * v.x;
        acc.y += nm * v.y;
    }
    float2 ag = *(const float2*)&agg[base];
    float2 b1 = *(const float2*)&bl[2 * lane];
    float2 b2 = *(const float2*)&bg[2 * lane];
    float2 a  = *(const float2*)&A[base];
    float2 l  = *(const float2*)&Lr[base];
    float v0 = ag.x + acc.x + b1.x + b2.x;
    float v1 = ag.y + acc.y + b1.y + b2.y;
    float w0 = 1.0f / (1.0f + __expf(-v0));
    float w1 = 1.0f / (1.0f + __expf(-v1));
    float o0 = 2.0f * (a.x * w0 + l.x * (1.0f - w0));
    float o1 = 2.0f * (a.y * w1 + l.y * (1.0f - w1));
    *(float2*)&agg[base] = make_float2(o0, o1);   // safe: own row only
}

extern "C" void kernel_launch(void* const* d_in, const int* in_sizes, int n_in,
                              void* d_out, int out_size, void* d_ws, size_t ws_size,
                              hipStream_t stream)
{
    const float* activity = (const float*)d_in[0];
    const float* learning = (const float*)d_in[1];
    const int*   ei  = (const int*)d_in[2];
    const float* ew  = (const float*)d_in[3];
    const int*   gei = (const int*)d_in[4];
    const float* gew = (const float*)d_in[5];
    const float* Wl  = (const float*)d_in[6];
    const float* bl  = (const float*)d_in[7];
    const float* Wg  = (const float*)d_in[8];
    const float* bg  = (const float*)d_in[9];

    const int n  = in_sizes[0] / DFEAT;   // 50000
    const int El = in_sizes[3];           // 500000
    const int Eg = in_sizes[5];           // 600000
    const int n2 = 2 * n;
    const int E  = El + Eg;

    // ws layout:
    // [agg fp32 N*128 | deg fp32 2N | cnt int 2N | ptr int 2N | bsum int (pad 2048B) | edata int2 E]
    char* ws = (char*)d_ws;
    const size_t aggBytes = (size_t)n * DFEAT * sizeof(float);
    float* agg  = (float*)ws;
    float* deg  = (float*)(ws + aggBytes);
    int*   cnt  = (int*)(ws + aggBytes + (size_t)n2 * 4);
    int*   ptr  = (int*)(ws + aggBytes + (size_t)n2 * 8);
    int*   bsum = (int*)(ws + aggBytes + (size_t)n2 * 12);
    int2*  edata = (int2*)(ws + aggBytes + (size_t)n2 * 12 + 2048);

    float* xw = (float*)d_out;            // staging for xw_l then xw_g

    const int scanBlocks = (n2 + 255) / 256;   // 391 (<=512 for scan2)

    // zero deg + cnt (contiguous)
    hipMemsetAsync(deg, 0, (size_t)n2 * 8, stream);

    hist_kernel<<<dim3((El + 255) / 256), dim3(256), 0, stream>>>(ei + El, ew, deg, cnt, 0, El);
    hist_kernel<<<dim3((Eg + 255) / 256), dim3(256), 0, stream>>>(gei + Eg, gew, deg, cnt, n, Eg);
    dinv_kernel<<<dim3((n2 + 255) / 256), dim3(256), 0, stream>>>(deg, n2);

    scan1_kernel<<<dim3(scanBlocks), dim3(256), 0, stream>>>(cnt, ptr, bsum, n2);
    scan2_kernel<<<dim3(1), dim3(512), 0, stream>>>(bsum, scanBlocks);
    scan3_kernel<<<dim3(scanBlocks), dim3(256), 0, stream>>>(ptr, bsum, n2);

    pos_scatter_kernel<<<dim3((El + 255) / 256), dim3(256), 0, stream>>>(
        ei, ei + El, ew, deg, ptr, edata, 0, El);
    pos_scatter_kernel<<<dim3((Eg + 255) / 256), dim3(256), 0, stream>>>(
        gei, gei + Eg, gew, deg, ptr, edata, n, Eg);

    const int gemmGrid = (n + GEMM_ROWS - 1) / GEMM_ROWS;
    const int nodeGrid = (n + 3) / 4;

    // ---- local branch ----
    gemm_kernel<<<dim3(gemmGrid), dim3(256), 0, stream>>>(activity, learning, Wl, xw, n);
    gather_local_kernel<<<dim3(nodeGrid), dim3(256), 0, stream>>>(xw, ptr, edata, deg, agg, n);

    // ---- global branch + fused epilogue ----
    gemm_kernel<<<dim3(gemmGrid), dim3(256), 0, stream>>>(activity, learning, Wg, xw, n);
    gather_global_kernel<<<dim3(nodeGrid), dim3(256), 0, stream>>>(
        xw, ptr, edata, deg, activity, learning, bl, bg, agg, n);

    // final result currently in agg -> copy to d_out
    hipMemcpyAsync(d_out, agg, aggBytes, hipMemcpyDeviceToDevice, stream);
}

// Round 5
// 408.348 us; speedup vs baseline: 3.0241x; 1.3327x over previous
//
#include <hip/hip_runtime.h>

#define DFEAT 128

typedef __attribute__((ext_vector_type(8))) short short8;
typedef __attribute__((ext_vector_type(4))) float float4v;

// ---------- bf16 helpers ----------
__device__ __forceinline__ float bf2f(unsigned int h) {
    union { unsigned int u; float f; } v; v.u = h << 16; return v.f;
}
__device__ __forceinline__ unsigned short f2bf(float f) {
    union { float f; unsigned int u; } v; v.f = f;
    unsigned int u = v.u;
    unsigned int lsb = (u >> 16) & 1u;
    u += 0x7fffu + lsb;               // RNE
    return (unsigned short)(u >> 16);
}

// ---------- prep: xa_bf16 = bf16(A + L), 4 elems/thread ----------
__global__ __launch_bounds__(256) void prep_xa_kernel(
    const float* __restrict__ A, const float* __restrict__ L,
    unsigned short* __restrict__ xa, int total4)   // total4 = n*128/4
{
    int i = blockIdx.x * 256 + threadIdx.x;
    if (i >= total4) return;
    float4 a = *(const float4*)&A[i * 4];
    float4 l = *(const float4*)&L[i * 4];
    ushort4 pk;
    pk.x = f2bf(a.x + l.x); pk.y = f2bf(a.y + l.y);
    pk.z = f2bf(a.z + l.z); pk.w = f2bf(a.w + l.w);
    *(ushort4*)&xa[i * 4] = pk;
}

// ---------- prep: WT[m][c][k] = bf16(W_m[k][c]) ----------
__global__ __launch_bounds__(256) void prep_w_kernel(
    const float* __restrict__ Wl, const float* __restrict__ Wg,
    unsigned short* __restrict__ WT)
{
    int idx = blockIdx.x * 256 + threadIdx.x;     // 0 .. 32767
    if (idx >= 2 * 128 * 128) return;
    int m = idx >> 14, rem = idx & 16383;
    int k = rem >> 7, c = rem & 127;              // lanes -> c consecutive (coalesced read)
    const float* W = m ? Wg : Wl;
    WT[m * 16384 + c * 128 + k] = f2bf(W[k * 128 + c]);
}

// ---------- fused histogram over both graphs ----------
__global__ __launch_bounds__(256) void hist_kernel(
    const int* __restrict__ dstL, const float* __restrict__ wL,
    const int* __restrict__ dstG, const float* __restrict__ wG,
    float* __restrict__ deg, int* __restrict__ cnt, int El, int Eg, int n)
{
    int e = blockIdx.x * 256 + threadIdx.x;
    if (e < El) {
        int t = dstL[e];
        atomicAdd(&deg[t], wL[e]);
        atomicAdd(&cnt[t], 1);
    } else if (e < El + Eg) {
        int e2 = e - El;
        int t = dstG[e2];
        atomicAdd(&deg[n + t], wG[e2]);
        atomicAdd(&cnt[n + t], 1);
    }
}

// ---------- scan stage 1 (+ fused dinv = rsqrt(deg+1)) ----------
__global__ __launch_bounds__(256) void scan1_kernel(const int* __restrict__ cnt,
                                                    int* __restrict__ ptr,
                                                    int* __restrict__ bsum,
                                                    float* __restrict__ deg, int n)
{
    __shared__ int tmp[256];
    int i = blockIdx.x * 256 + threadIdx.x;
    if (i < n) deg[i] = rsqrtf(deg[i] + 1.0f);
    int v = (i < n) ? cnt[i] : 0;
    tmp[threadIdx.x] = v;
    __syncthreads();
    for (int off = 1; off < 256; off <<= 1) {
        int t = (threadIdx.x >= off) ? tmp[threadIdx.x - off] : 0;
        __syncthreads();
        tmp[threadIdx.x] += t;
        __syncthreads();
    }
    if (i < n) ptr[i] = tmp[threadIdx.x] - v;
    if (threadIdx.x == 255) bsum[blockIdx.x] = tmp[255];
}

// ---------- scan stage 2: single block (nb <= 512) ----------
__global__ __launch_bounds__(512) void scan2_kernel(int* __restrict__ bsum, int nb)
{
    __shared__ int tmp[512];
    int i = threadIdx.x;
    int v = (i < nb) ? bsum[i] : 0;
    tmp[i] = v;
    __syncthreads();
    for (int off = 1; off < 512; off <<= 1) {
        int t = (i >= off) ? tmp[i - off] : 0;
        __syncthreads();
        tmp[i] += t;
        __syncthreads();
    }
    if (i < nb) bsum[i] = tmp[i] - v;
}

// ---------- scan stage 3 ----------
__global__ __launch_bounds__(256) void scan3_kernel(int* __restrict__ ptr,
                                                    const int* __restrict__ bsum, int n)
{
    int i = blockIdx.x * 256 + threadIdx.x;
    if (i < n) ptr[i] += bsum[blockIdx.x];
}

// ---------- fused position scatter (both graphs); destroys ptr -> end offsets ----------
__global__ __launch_bounds__(256) void pos_scatter_kernel(
    const int* __restrict__ srcL, const int* __restrict__ dstL, const float* __restrict__ wL,
    const int* __restrict__ srcG, const int* __restrict__ dstG, const float* __restrict__ wG,
    const float* __restrict__ dinv, int* __restrict__ ptr, int2* __restrict__ edata,
    int El, int Eg, int n)
{
    int e = blockIdx.x * 256 + threadIdx.x;
    if (e < El) {
        int s = srcL[e], t = dstL[e];
        float norm = dinv[s] * wL[e] * dinv[t];
        int pos = atomicAdd(&ptr[t], 1);
        edata[pos] = make_int2(__float_as_int(norm), s);
    } else if (e < El + Eg) {
        int e2 = e - El;
        int s = srcG[e2], t = dstG[e2];
        float norm = dinv[n + s] * wG[e2] * dinv[n + t];
        int pos = atomicAdd(&ptr[n + t], 1);
        edata[pos] = make_int2(__float_as_int(norm), s);
    }
}

// ---------- MFMA dual GEMM: xw_{l,g} = xa @ W_{l,g}, all bf16 in/out, fp32 acc ----------
// Block: 256 thr (4 waves), 64 rows. LDS: both W^T, pitch 272 B (16-aligned, bank-uniform).
__global__ __launch_bounds__(256) void gemm_kernel(
    const unsigned short* __restrict__ xa,   // [n][128] bf16
    const unsigned short* __restrict__ WT,   // [2][128 col][128 k] bf16
    unsigned short* __restrict__ xwl,
    unsigned short* __restrict__ xwg, int n)
{
    __shared__ unsigned short sWT[2 * 128 * 136];   // 69632 B, pitch 272 B
    const int tid = threadIdx.x;

    { // stage both W^T: 4096 uint4
        const uint4* wtv = (const uint4*)WT;
        #pragma unroll
        for (int it = 0; it < 16; ++it) {
            int idx = it * 256 + tid;
            int m = idx >> 11, rem = idx & 2047;
            int col = rem >> 4, chunk = rem & 15;
            *(uint4*)((char*)sWT + m * 34816 + col * 272 + chunk * 16) = wtv[idx];
        }
    }
    __syncthreads();

    const int wid  = tid >> 6;
    const int lane = tid & 63;
    const int quad = lane >> 4;
    const int cl   = lane & 15;
    const int rowa = blockIdx.x * 64 + wid * 16 + cl;   // A-frag row (may run past n; stays in xa buffer)

    short8 a[4];
    const char* xab = (const char*)xa + (size_t)rowa * 256 + quad * 16;
    #pragma unroll
    for (int kk = 0; kk < 4; ++kk)
        a[kk] = *(const short8*)(xab + kk * 64);

    const int rbase = blockIdx.x * 64 + wid * 16 + quad * 4;

    #pragma unroll
    for (int m = 0; m < 2; ++m) {
        unsigned short* out = m ? xwg : xwl;
        const char* wb = (const char*)sWT + m * 34816 + quad * 16;
        #pragma unroll
        for (int t = 0; t < 8; ++t) {
            float4v acc = {0.f, 0.f, 0.f, 0.f};
            const char* wbc = wb + (t * 16 + cl) * 272;
            #pragma unroll
            for (int kk = 0; kk < 4; ++kk) {
                short8 b = *(const short8*)(wbc + kk * 64);
                acc = __builtin_amdgcn_mfma_f32_16x16x32_bf16(a[kk], b, acc, 0, 0, 0);
            }
            int colo = t * 16 + cl;
            #pragma unroll
            for (int r = 0; r < 4; ++r) {
                int ro = rbase + r;
                if (ro < n) out[(size_t)ro * DFEAT + colo] = f2bf(acc[r]);
            }
        }
    }
}

// ---------- fused gather (local + global + epilogue), bf16 rows, writes d_out ----------
__global__ __launch_bounds__(256) void gather_kernel(
    const unsigned short* __restrict__ xwl, const unsigned short* __restrict__ xwg,
    const int* __restrict__ ptr, const int2* __restrict__ edata,
    const float* __restrict__ dinv,
    const float* __restrict__ A, const float* __restrict__ Lr,
    const float* __restrict__ bl, const float* __restrict__ bg,
    float* __restrict__ out, int n)
{
    const int lane = threadIdx.x & 63;
    const int node = blockIdx.x * 4 + (threadIdx.x >> 6);
    if (node >= n) return;
    int i0l = node ? ptr[node - 1] : 0;
    int i1l = ptr[node];
    int i0g = ptr[n + node - 1];
    int i1g = ptr[n + node];
    float dl = dinv[node];     dl *= dl;
    float dg = dinv[n + node]; dg *= dg;
    const int fo = 2 * lane;
    const size_t base = (size_t)node * DFEAT + fo;

    unsigned int psl = *(const unsigned int*)&xwl[base];
    unsigned int psg = *(const unsigned int*)&xwg[base];
    float acc0 = dl * bf2f(psl & 0xffffu) + dg * bf2f(psg & 0xffffu);
    float acc1 = dl * bf2f(psl >> 16)     + dg * bf2f(psg >> 16);

    for (int j = i0l; j < i1l; ++j) {
        int2 ed = edata[j];
        float nm = __int_as_float(ed.x);
        unsigned int pk = *(const unsigned int*)&xwl[(size_t)ed.y * DFEAT + fo];
        acc0 += nm * bf2f(pk & 0xffffu);
        acc1 += nm * bf2f(pk >> 16);
    }
    for (int j = i0g; j < i1g; ++j) {
        int2 ed = edata[j];
        float nm = __int_as_float(ed.x);
        unsigned int pk = *(const unsigned int*)&xwg[(size_t)ed.y * DFEAT + fo];
        acc0 += nm * bf2f(pk & 0xffffu);
        acc1 += nm * bf2f(pk >> 16);
    }

    float2 b1 = *(const float2*)&bl[fo];
    float2 b2 = *(const float2*)&bg[fo];
    float2 a2 = *(const float2*)&A[base];
    float2 l2 = *(const float2*)&Lr[base];
    float v0 = acc0 + b1.x + b2.x;
    float v1 = acc1 + b1.y + b2.y;
    float w0 = 1.0f / (1.0f + __expf(-v0));
    float w1 = 1.0f / (1.0f + __expf(-v1));
    float o0 = 2.0f * (a2.x * w0 + l2.x * (1.0f - w0));
    float o1 = 2.0f * (a2.y * w1 + l2.y * (1.0f - w1));
    *(float2*)&out[base] = make_float2(o0, o1);
}

extern "C" void kernel_launch(void* const* d_in, const int* in_sizes, int n_in,
                              void* d_out, int out_size, void* d_ws, size_t ws_size,
                              hipStream_t stream)
{
    const float* activity = (const float*)d_in[0];
    const float* learning = (const float*)d_in[1];
    const int*   ei  = (const int*)d_in[2];
    const float* ew  = (const float*)d_in[3];
    const int*   gei = (const int*)d_in[4];
    const float* gew = (const float*)d_in[5];
    const float* Wl  = (const float*)d_in[6];
    const float* bl  = (const float*)d_in[7];
    const float* Wg  = (const float*)d_in[8];
    const float* bg  = (const float*)d_in[9];

    const int n  = in_sizes[0] / DFEAT;   // 50000
    const int El = in_sizes[3];           // 500000
    const int Eg = in_sizes[5];           // 600000
    const int n2 = 2 * n;
    const int E  = El + Eg;

    // ws layout (~35.7 MB):
    // [xwl bf16 n*128][xwg bf16 n*128][deg f32 2N][cnt 2N][ptr 2N][bsum 2048B][WT bf16 2*128*128][edata int2 E]
    char* ws = (char*)d_ws;
    const size_t xwBytes = (size_t)n * DFEAT * 2;
    unsigned short* xwl = (unsigned short*)ws;
    unsigned short* xwg = (unsigned short*)(ws + xwBytes);
    float* deg  = (float*)(ws + 2 * xwBytes);
    int*   cnt  = (int*)(ws + 2 * xwBytes + (size_t)n2 * 4);
    int*   ptr  = (int*)(ws + 2 * xwBytes + (size_t)n2 * 8);
    int*   bsum = (int*)(ws + 2 * xwBytes + (size_t)n2 * 12);
    unsigned short* WT = (unsigned short*)(ws + 2 * xwBytes + (size_t)n2 * 12 + 2048);
    int2* edata = (int2*)(ws + 2 * xwBytes + (size_t)n2 * 12 + 2048 + 2 * 128 * 128 * 2);

    unsigned short* xa = (unsigned short*)d_out;   // xa_bf16 staged in d_out; dead before gather writes

    const int scanBlocks = (n2 + 255) / 256;       // 391

    hipMemsetAsync(deg, 0, (size_t)n2 * 8, stream);  // deg + cnt

    prep_xa_kernel<<<dim3((n * 32 + 255) / 256), dim3(256), 0, stream>>>(activity, learning, xa, n * 32);
    prep_w_kernel<<<dim3(128), dim3(256), 0, stream>>>(Wl, Wg, WT);

    hist_kernel<<<dim3((E + 255) / 256), dim3(256), 0, stream>>>(
        ei + El, ew, gei + Eg, gew, deg, cnt, El, Eg, n);

    scan1_kernel<<<dim3(scanBlocks), dim3(256), 0, stream>>>(cnt, ptr, bsum, deg, n2);
    scan2_kernel<<<dim3(1), dim3(512), 0, stream>>>(bsum, scanBlocks);
    scan3_kernel<<<dim3(scanBlocks), dim3(256), 0, stream>>>(ptr, bsum, n2);

    pos_scatter_kernel<<<dim3((E + 255) / 256), dim3(256), 0, stream>>>(
        ei, ei + El, ew, gei, gei + Eg, gew, deg, ptr, edata, El, Eg, n);

    gemm_kernel<<<dim3((n + 63) / 64), dim3(256), 0, stream>>>(xa, WT, xwl, xwg, n);

    gather_kernel<<<dim3((n + 3) / 4), dim3(256), 0, stream>>>(
        xwl, xwg, ptr, edata, deg, activity, learning, bl, bg, (float*)d_out, n);
}

// Round 6
// 383.470 us; speedup vs baseline: 3.2203x; 1.0649x over previous
//
#include <hip/hip_runtime.h>

#define DFEAT 128

typedef __attribute__((ext_vector_type(8))) short short8;
typedef __attribute__((ext_vector_type(4))) float float4v;

// ---------- bf16 helpers ----------
__device__ __forceinline__ float bf2f(unsigned int h) {
    union { unsigned int u; float f; } v; v.u = h << 16; return v.f;
}
__device__ __forceinline__ unsigned short f2bf(float f) {
    union { float f; unsigned int u; } v; v.f = f;
    unsigned int u = v.u;
    unsigned int lsb = (u >> 16) & 1u;
    u += 0x7fffu + lsb;               // RNE
    return (unsigned short)(u >> 16);
}

// ---------- prep: WT[m][c][k] = bf16(W_m[k][c]) ----------
__global__ __launch_bounds__(256) void prep_w_kernel(
    const float* __restrict__ Wl, const float* __restrict__ Wg,
    unsigned short* __restrict__ WT)
{
    int idx = blockIdx.x * 256 + threadIdx.x;     // 0 .. 32767
    if (idx >= 2 * 128 * 128) return;
    int m = idx >> 14, rem = idx & 16383;
    int k = rem >> 7, c = rem & 127;              // lanes -> c consecutive (coalesced read)
    const float* W = m ? Wg : Wl;
    WT[m * 16384 + c * 128 + k] = f2bf(W[k * 128 + c]);
}

// ---------- fused histogram over both graphs ----------
__global__ __launch_bounds__(256) void hist_kernel(
    const int* __restrict__ dstL, const float* __restrict__ wL,
    const int* __restrict__ dstG, const float* __restrict__ wG,
    float* __restrict__ deg, int* __restrict__ cnt, int El, int Eg, int n)
{
    int e = blockIdx.x * 256 + threadIdx.x;
    if (e < El) {
        int t = dstL[e];
        atomicAdd(&deg[t], wL[e]);
        atomicAdd(&cnt[t], 1);
    } else if (e < El + Eg) {
        int e2 = e - El;
        int t = dstG[e2];
        atomicAdd(&deg[n + t], wG[e2]);
        atomicAdd(&cnt[n + t], 1);
    }
}

// ---------- scan stage 1 (+ fused dinv = rsqrt(deg+1)) ----------
__global__ __launch_bounds__(256) void scan1_kernel(const int* __restrict__ cnt,
                                                    int* __restrict__ ptr,
                                                    int* __restrict__ bsum,
                                                    float* __restrict__ deg, int n)
{
    __shared__ int tmp[256];
    int i = blockIdx.x * 256 + threadIdx.x;
    if (i < n) deg[i] = rsqrtf(deg[i] + 1.0f);
    int v = (i < n) ? cnt[i] : 0;
    tmp[threadIdx.x] = v;
    __syncthreads();
    for (int off = 1; off < 256; off <<= 1) {
        int t = (threadIdx.x >= off) ? tmp[threadIdx.x - off] : 0;
        __syncthreads();
        tmp[threadIdx.x] += t;
        __syncthreads();
    }
    if (i < n) ptr[i] = tmp[threadIdx.x] - v;
    if (threadIdx.x == 255) bsum[blockIdx.x] = tmp[255];
}

// ---------- scan stage 2: single block (nb <= 512) ----------
__global__ __launch_bounds__(512) void scan2_kernel(int* __restrict__ bsum, int nb)
{
    __shared__ int tmp[512];
    int i = threadIdx.x;
    int v = (i < nb) ? bsum[i] : 0;
    tmp[i] = v;
    __syncthreads();
    for (int off = 1; off < 512; off <<= 1) {
        int t = (i >= off) ? tmp[i - off] : 0;
        __syncthreads();
        tmp[i] += t;
        __syncthreads();
    }
    if (i < nb) bsum[i] = tmp[i] - v;
}

// ---------- scan stage 3 ----------
__global__ __launch_bounds__(256) void scan3_kernel(int* __restrict__ ptr,
                                                    const int* __restrict__ bsum, int n)
{
    int i = blockIdx.x * 256 + threadIdx.x;
    if (i < n) ptr[i] += bsum[blockIdx.x];
}

// ---------- fused position scatter (both graphs); destroys ptr -> end offsets ----------
__global__ __launch_bounds__(256) void pos_scatter_kernel(
    const int* __restrict__ srcL, const int* __restrict__ dstL, const float* __restrict__ wL,
    const int* __restrict__ srcG, const int* __restrict__ dstG, const float* __restrict__ wG,
    const float* __restrict__ dinv, int* __restrict__ ptr, int2* __restrict__ edata,
    int El, int Eg, int n)
{
    int e = blockIdx.x * 256 + threadIdx.x;
    if (e < El) {
        int s = srcL[e], t = dstL[e];
        float norm = dinv[s] * wL[e] * dinv[t];
        int pos = atomicAdd(&ptr[t], 1);
        edata[pos] = make_int2(__float_as_int(norm), s);
    } else if (e < El + Eg) {
        int e2 = e - El;
        int s = srcG[e2], t = dstG[e2];
        float norm = dinv[n + s] * wG[e2] * dinv[n + t];
        int pos = atomicAdd(&ptr[n + t], 1);
        edata[pos] = make_int2(__float_as_int(norm), s);
    }
}

// ---------- MFMA dual GEMM, no LDS: xw_{l,g} = bf16(A+L) @ W_{l,g} ----------
// A-frags built in-register from fp32 A,L (fuses prep_xa). B-frags straight from
// global WT (64 KB, L1/L2-resident, shared by all blocks). 4 waves x 16 rows.
__global__ __launch_bounds__(256) void gemm_kernel(
    const float* __restrict__ A, const float* __restrict__ L,
    const unsigned short* __restrict__ WT,   // [2][col 128][k 128] bf16
    unsigned short* __restrict__ xwl,
    unsigned short* __restrict__ xwg, int n)
{
    const int tid  = threadIdx.x;
    const int wid  = tid >> 6;
    const int lane = tid & 63;
    const int quad = lane >> 4;
    const int cl   = lane & 15;

    int rowa = blockIdx.x * 64 + wid * 16 + cl;
    if (rowa > n - 1) rowa = n - 1;               // clamp (dup compute, stores predicated)

    const float* Ar = A + (size_t)rowa * DFEAT;
    const float* Lr = L + (size_t)rowa * DFEAT;

    short8 a[4];
    #pragma unroll
    for (int kk = 0; kk < 4; ++kk) {
        const int kb = kk * 32 + quad * 8;
        float4 a0 = *(const float4*)&Ar[kb];
        float4 a1 = *(const float4*)&Ar[kb + 4];
        float4 l0 = *(const float4*)&Lr[kb];
        float4 l1 = *(const float4*)&Lr[kb + 4];
        union { short8 v; unsigned short u[8]; } s;
        s.u[0] = f2bf(a0.x + l0.x); s.u[1] = f2bf(a0.y + l0.y);
        s.u[2] = f2bf(a0.z + l0.z); s.u[3] = f2bf(a0.w + l0.w);
        s.u[4] = f2bf(a1.x + l1.x); s.u[5] = f2bf(a1.y + l1.y);
        s.u[6] = f2bf(a1.z + l1.z); s.u[7] = f2bf(a1.w + l1.w);
        a[kk] = s.v;
    }

    const int rbase = blockIdx.x * 64 + wid * 16 + quad * 4;
    const char* wtb = (const char*)WT + quad * 16;

    #pragma unroll
    for (int m = 0; m < 2; ++m) {
        unsigned short* out = m ? xwg : xwl;
        #pragma unroll
        for (int t = 0; t < 8; ++t) {
            const int col = t * 16 + cl;
            const char* bp = wtb + m * 32768 + col * 256;
            float4v acc = {0.f, 0.f, 0.f, 0.f};
            #pragma unroll
            for (int kk = 0; kk < 4; ++kk) {
                short8 b = *(const short8*)(bp + kk * 64);
                acc = __builtin_amdgcn_mfma_f32_16x16x32_bf16(a[kk], b, acc, 0, 0, 0);
            }
            #pragma unroll
            for (int r = 0; r < 4; ++r) {
                int ro = rbase + r;
                if (ro < n) out[(size_t)ro * DFEAT + col] = f2bf(acc[r]);
            }
        }
    }
}

// ---------- fused gather: shuffle-broadcast edge metadata for MLP ----------
__global__ __launch_bounds__(256) void gather_kernel(
    const unsigned short* __restrict__ xwl, const unsigned short* __restrict__ xwg,
    const int* __restrict__ ptr, const int2* __restrict__ edata,
    const float* __restrict__ dinv,
    const float* __restrict__ A, const float* __restrict__ Lr,
    const float* __restrict__ bl, const float* __restrict__ bg,
    float* __restrict__ out, int n)
{
    const int lane = threadIdx.x & 63;
    const int node = blockIdx.x * 4 + (threadIdx.x >> 6);
    if (node >= n) return;
    const int i0l = node ? ptr[node - 1] : 0;
    const int i1l = ptr[node];
    const int i0g = ptr[n + node - 1];
    const int i1g = ptr[n + node];
    float dl = dinv[node];     dl *= dl;
    float dg = dinv[n + node]; dg *= dg;
    const int fo = 2 * lane;
    const size_t base = (size_t)node * DFEAT + fo;

    unsigned int psl = *(const unsigned int*)&xwl[base];
    unsigned int psg = *(const unsigned int*)&xwg[base];
    float acc0 = dl * bf2f(psl & 0xffffu) + dg * bf2f(psg & 0xffffu);
    float acc1 = dl * bf2f(psl >> 16)     + dg * bf2f(psg >> 16);

    // ---- local segment ----
    for (int b0 = i0l; b0 < i1l; b0 += 64) {
        int idx = b0 + lane;
        int2 ed = edata[idx < i1l ? idx : (i1l - 1)];   // coalesced preload of <=64 edges
        float nmv = __int_as_float(ed.x);
        int   sv  = ed.y;
        int mcnt = i1l - b0; if (mcnt > 64) mcnt = 64;
        #pragma unroll 4
        for (int jj = 0; jj < mcnt; ++jj) {
            float nm = __shfl(nmv, jj);
            int   s  = __shfl(sv, jj);
            unsigned int pk = *(const unsigned int*)&xwl[(size_t)s * DFEAT + fo];
            acc0 += nm * bf2f(pk & 0xffffu);
            acc1 += nm * bf2f(pk >> 16);
        }
    }
    // ---- global segment ----
    for (int b0 = i0g; b0 < i1g; b0 += 64) {
        int idx = b0 + lane;
        int2 ed = edata[idx < i1g ? idx : (i1g - 1)];
        float nmv = __int_as_float(ed.x);
        int   sv  = ed.y;
        int mcnt = i1g - b0; if (mcnt > 64) mcnt = 64;
        #pragma unroll 4
        for (int jj = 0; jj < mcnt; ++jj) {
            float nm = __shfl(nmv, jj);
            int   s  = __shfl(sv, jj);
            unsigned int pk = *(const unsigned int*)&xwg[(size_t)s * DFEAT + fo];
            acc0 += nm * bf2f(pk & 0xffffu);
            acc1 += nm * bf2f(pk >> 16);
        }
    }

    float2 b1 = *(const float2*)&bl[fo];
    float2 b2 = *(const float2*)&bg[fo];
    float2 a2 = *(const float2*)&A[base];
    float2 l2 = *(const float2*)&Lr[base];
    float v0 = acc0 + b1.x + b2.x;
    float v1 = acc1 + b1.y + b2.y;
    float w0 = 1.0f / (1.0f + __expf(-v0));
    float w1 = 1.0f / (1.0f + __expf(-v1));
    float o0 = 2.0f * (a2.x * w0 + l2.x * (1.0f - w0));
    float o1 = 2.0f * (a2.y * w1 + l2.y * (1.0f - w1));
    *(float2*)&out[base] = make_float2(o0, o1);
}

extern "C" void kernel_launch(void* const* d_in, const int* in_sizes, int n_in,
                              void* d_out, int out_size, void* d_ws, size_t ws_size,
                              hipStream_t stream)
{
    const float* activity = (const float*)d_in[0];
    const float* learning = (const float*)d_in[1];
    const int*   ei  = (const int*)d_in[2];
    const float* ew  = (const float*)d_in[3];
    const int*   gei = (const int*)d_in[4];
    const float* gew = (const float*)d_in[5];
    const float* Wl  = (const float*)d_in[6];
    const float* bl  = (const float*)d_in[7];
    const float* Wg  = (const float*)d_in[8];
    const float* bg  = (const float*)d_in[9];

    const int n  = in_sizes[0] / DFEAT;   // 50000
    const int El = in_sizes[3];           // 500000
    const int Eg = in_sizes[5];           // 600000
    const int n2 = 2 * n;
    const int E  = El + Eg;

    // ws layout (~35.7 MB, same as round 5):
    // [xwl bf16 n*128][xwg bf16 n*128][deg f32 2N][cnt 2N][ptr 2N][bsum 2048B][WT bf16 2*128*128][edata int2 E]
    char* ws = (char*)d_ws;
    const size_t xwBytes = (size_t)n * DFEAT * 2;
    unsigned short* xwl = (unsigned short*)ws;
    unsigned short* xwg = (unsigned short*)(ws + xwBytes);
    float* deg  = (float*)(ws + 2 * xwBytes);
    int*   cnt  = (int*)(ws + 2 * xwBytes + (size_t)n2 * 4);
    int*   ptr  = (int*)(ws + 2 * xwBytes + (size_t)n2 * 8);
    int*   bsum = (int*)(ws + 2 * xwBytes + (size_t)n2 * 12);
    unsigned short* WT = (unsigned short*)(ws + 2 * xwBytes + (size_t)n2 * 12 + 2048);
    int2* edata = (int2*)(ws + 2 * xwBytes + (size_t)n2 * 12 + 2048 + 2 * 128 * 128 * 2);

    const int scanBlocks = (n2 + 255) / 256;       // 391

    hipMemsetAsync(deg, 0, (size_t)n2 * 8, stream);  // deg + cnt

    prep_w_kernel<<<dim3(128), dim3(256), 0, stream>>>(Wl, Wg, WT);

    hist_kernel<<<dim3((E + 255) / 256), dim3(256), 0, stream>>>(
        ei + El, ew, gei + Eg, gew, deg, cnt, El, Eg, n);

    scan1_kernel<<<dim3(scanBlocks), dim3(256), 0, stream>>>(cnt, ptr, bsum, deg, n2);
    scan2_kernel<<<dim3(1), dim3(512), 0, stream>>>(bsum, scanBlocks);
    scan3_kernel<<<dim3(scanBlocks), dim3(256), 0, stream>>>(ptr, bsum, n2);

    pos_scatter_kernel<<<dim3((E + 255) / 256), dim3(256), 0, stream>>>(
        ei, ei + El, ew, gei, gei + Eg, gew, deg, ptr, edata, El, Eg, n);

    gemm_kernel<<<dim3((n + 63) / 64), dim3(256), 0, stream>>>(
        activity, learning, WT, xwl, xwg, n);

    gather_kernel<<<dim3((n + 3) / 4), dim3(256), 0, stream>>>(
        xwl, xwg, ptr, edata, deg, activity, learning, bl, bg, (float*)d_out, n);
}

// Round 7
// 333.902 us; speedup vs baseline: 3.6984x; 1.1484x over previous
//
#include <hip/hip_runtime.h>

#define DFEAT 128

typedef __attribute__((ext_vector_type(8))) short short8;
typedef __attribute__((ext_vector_type(4))) float float4v;

// ---------- bf16 helpers ----------
__device__ __forceinline__ float bf2f(unsigned int h) {
    union { unsigned int u; float f; } v; v.u = h << 16; return v.f;
}
__device__ __forceinline__ unsigned short f2bf(float f) {
    union { float f; unsigned int u; } v; v.f = f;
    unsigned int u = v.u;
    unsigned int lsb = (u >> 16) & 1u;
    u += 0x7fffu + lsb;               // RNE
    return (unsigned short)(u >> 16);
}

// ---------- fused: prep_w (blocks [0,128)) + packed-u64 histogram (rest) ----------
// dc[t] += (1<<48) | (u64)(w * 2^40)   -- count in hi 16, fixed-point wsum in lo 48.
__global__ __launch_bounds__(256) void hist_kernel(
    const int* __restrict__ dstL, const float* __restrict__ wL,
    const int* __restrict__ dstG, const float* __restrict__ wG,
    const float* __restrict__ Wl, const float* __restrict__ Wg,
    unsigned short* __restrict__ WT,
    unsigned long long* __restrict__ dc, int El, int Eg, int n)
{
    if (blockIdx.x < 128) {
        int idx = blockIdx.x * 256 + threadIdx.x;     // 0 .. 32767
        int m = idx >> 14, rem = idx & 16383;
        int k = rem >> 7, c = rem & 127;
        const float* W = m ? Wg : Wl;
        WT[m * 16384 + c * 128 + k] = f2bf(W[k * 128 + c]);
        return;
    }
    int e = (blockIdx.x - 128) * 256 + threadIdx.x;
    if (e < El) {
        int t = dstL[e];
        unsigned long long add = (1ULL << 48) | (unsigned long long)(wL[e] * 0x1p40f);
        atomicAdd(&dc[t], add);
    } else if (e < El + Eg) {
        int e2 = e - El;
        int t = dstG[e2];
        unsigned long long add = (1ULL << 48) | (unsigned long long)(wG[e2] * 0x1p40f);
        atomicAdd(&dc[n + t], add);
    }
}

// ---------- scan stage 1: unpack dc -> (cnt scan into ptr, dinv) ----------
__global__ __launch_bounds__(256) void scan1_kernel(const unsigned long long* __restrict__ dc,
                                                    int* __restrict__ ptr,
                                                    int* __restrict__ bsum,
                                                    float* __restrict__ dinv, int n)
{
    __shared__ int tmp[256];
    int i = blockIdx.x * 256 + threadIdx.x;
    int v = 0;
    if (i < n) {
        unsigned long long d = dc[i];
        v = (int)(d >> 48);
        dinv[i] = rsqrtf((float)(d & ((1ULL << 48) - 1)) * 0x1p-40f + 1.0f);
    }
    tmp[threadIdx.x] = v;
    __syncthreads();
    for (int off = 1; off < 256; off <<= 1) {
        int t = (threadIdx.x >= off) ? tmp[threadIdx.x - off] : 0;
        __syncthreads();
        tmp[threadIdx.x] += t;
        __syncthreads();
    }
    if (i < n) ptr[i] = tmp[threadIdx.x] - v;
    if (threadIdx.x == 255) bsum[blockIdx.x] = tmp[255];
}

// ---------- scan stage 2: single block (nb <= 512) ----------
__global__ __launch_bounds__(512) void scan2_kernel(int* __restrict__ bsum, int nb)
{
    __shared__ int tmp[512];
    int i = threadIdx.x;
    int v = (i < nb) ? bsum[i] : 0;
    tmp[i] = v;
    __syncthreads();
    for (int off = 1; off < 512; off <<= 1) {
        int t = (i >= off) ? tmp[i - off] : 0;
        __syncthreads();
        tmp[i] += t;
        __syncthreads();
    }
    if (i < nb) bsum[i] = tmp[i] - v;
}

// ---------- scan stage 3 ----------
__global__ __launch_bounds__(256) void scan3_kernel(int* __restrict__ ptr,
                                                    const int* __restrict__ bsum, int n)
{
    int i = blockIdx.x * 256 + threadIdx.x;
    if (i < n) ptr[i] += bsum[blockIdx.x];
}

// ---------- fused position scatter (both graphs); destroys ptr -> end offsets ----------
__global__ __launch_bounds__(256) void pos_scatter_kernel(
    const int* __restrict__ srcL, const int* __restrict__ dstL, const float* __restrict__ wL,
    const int* __restrict__ srcG, const int* __restrict__ dstG, const float* __restrict__ wG,
    const float* __restrict__ dinv, int* __restrict__ ptr, int2* __restrict__ edata,
    int El, int Eg, int n)
{
    int e = blockIdx.x * 256 + threadIdx.x;
    if (e < El) {
        int s = srcL[e], t = dstL[e];
        float norm = dinv[s] * wL[e] * dinv[t];
        int pos = atomicAdd(&ptr[t], 1);
        edata[pos] = make_int2(__float_as_int(norm), s);
    } else if (e < El + Eg) {
        int e2 = e - El;
        int s = srcG[e2], t = dstG[e2];
        float norm = dinv[n + s] * wG[e2] * dinv[n + t];
        int pos = atomicAdd(&ptr[n + t], 1);
        edata[pos] = make_int2(__float_as_int(norm), s);
    }
}

// ---------- MFMA dual GEMM, no LDS: xw_{l,g} = bf16(A+L) @ W_{l,g} ----------
__global__ __launch_bounds__(256) void gemm_kernel(
    const float* __restrict__ A, const float* __restrict__ L,
    const unsigned short* __restrict__ WT,   // [2][col 128][k 128] bf16
    unsigned short* __restrict__ xwl,
    unsigned short* __restrict__ xwg, int n)
{
    const int tid  = threadIdx.x;
    const int wid  = tid >> 6;
    const int lane = tid & 63;
    const int quad = lane >> 4;
    const int cl   = lane & 15;

    int rowa = blockIdx.x * 64 + wid * 16 + cl;
    if (rowa > n - 1) rowa = n - 1;               // clamp (dup compute, stores predicated)

    const float* Ar = A + (size_t)rowa * DFEAT;
    const float* Lr = L + (size_t)rowa * DFEAT;

    short8 a[4];
    #pragma unroll
    for (int kk = 0; kk < 4; ++kk) {
        const int kb = kk * 32 + quad * 8;
        float4 a0 = *(const float4*)&Ar[kb];
        float4 a1 = *(const float4*)&Ar[kb + 4];
        float4 l0 = *(const float4*)&Lr[kb];
        float4 l1 = *(const float4*)&Lr[kb + 4];
        union { short8 v; unsigned short u[8]; } s;
        s.u[0] = f2bf(a0.x + l0.x); s.u[1] = f2bf(a0.y + l0.y);
        s.u[2] = f2bf(a0.z + l0.z); s.u[3] = f2bf(a0.w + l0.w);
        s.u[4] = f2bf(a1.x + l1.x); s.u[5] = f2bf(a1.y + l1.y);
        s.u[6] = f2bf(a1.z + l1.z); s.u[7] = f2bf(a1.w + l1.w);
        a[kk] = s.v;
    }

    const int rbase = blockIdx.x * 64 + wid * 16 + quad * 4;
    const char* wtb = (const char*)WT + quad * 16;

    #pragma unroll
    for (int m = 0; m < 2; ++m) {
        unsigned short* out = m ? xwg : xwl;
        #pragma unroll
        for (int t = 0; t < 8; ++t) {
            const int col = t * 16 + cl;
            const char* bp = wtb + m * 32768 + col * 256;
            float4v acc = {0.f, 0.f, 0.f, 0.f};
            #pragma unroll
            for (int kk = 0; kk < 4; ++kk) {
                short8 b = *(const short8*)(bp + kk * 64);
                acc = __builtin_amdgcn_mfma_f32_16x16x32_bf16(a[kk], b, acc, 0, 0, 0);
            }
            #pragma unroll
            for (int r = 0; r < 4; ++r) {
                int ro = rbase + r;
                if (ro < n) out[(size_t)ro * DFEAT + col] = f2bf(acc[r]);
            }
        }
    }
}

// ---------- fused gather: shuffle-broadcast edge metadata for MLP ----------
__global__ __launch_bounds__(256) void gather_kernel(
    const unsigned short* __restrict__ xwl, const unsigned short* __restrict__ xwg,
    const int* __restrict__ ptr, const int2* __restrict__ edata,
    const float* __restrict__ dinv,
    const float* __restrict__ A, const float* __restrict__ Lr,
    const float* __restrict__ bl, const float* __restrict__ bg,
    float* __restrict__ out, int n)
{
    const int lane = threadIdx.x & 63;
    const int node = blockIdx.x * 4 + (threadIdx.x >> 6);
    if (node >= n) return;
    const int i0l = node ? ptr[node - 1] : 0;
    const int i1l = ptr[node];
    const int i0g = ptr[n + node - 1];
    const int i1g = ptr[n + node];
    float dl = dinv[node];     dl *= dl;
    float dg = dinv[n + node]; dg *= dg;
    const int fo = 2 * lane;
    const size_t base = (size_t)node * DFEAT + fo;

    unsigned int psl = *(const unsigned int*)&xwl[base];
    unsigned int psg = *(const unsigned int*)&xwg[base];
    float acc0 = dl * bf2f(psl & 0xffffu) + dg * bf2f(psg & 0xffffu);
    float acc1 = dl * bf2f(psl >> 16)     + dg * bf2f(psg >> 16);

    // ---- local segment ----
    for (int b0 = i0l; b0 < i1l; b0 += 64) {
        int idx = b0 + lane;
        int2 ed = edata[idx < i1l ? idx : (i1l - 1)];
        float nmv = __int_as_float(ed.x);
        int   sv  = ed.y;
        int mcnt = i1l - b0; if (mcnt > 64) mcnt = 64;
        #pragma unroll 4
        for (int jj = 0; jj < mcnt; ++jj) {
            float nm = __shfl(nmv, jj);
            int   s  = __shfl(sv, jj);
            unsigned int pk = *(const unsigned int*)&xwl[(size_t)s * DFEAT + fo];
            acc0 += nm * bf2f(pk & 0xffffu);
            acc1 += nm * bf2f(pk >> 16);
        }
    }
    // ---- global segment ----
    for (int b0 = i0g; b0 < i1g; b0 += 64) {
        int idx = b0 + lane;
        int2 ed = edata[idx < i1g ? idx : (i1g - 1)];
        float nmv = __int_as_float(ed.x);
        int   sv  = ed.y;
        int mcnt = i1g - b0; if (mcnt > 64) mcnt = 64;
        #pragma unroll 4
        for (int jj = 0; jj < mcnt; ++jj) {
            float nm = __shfl(nmv, jj);
            int   s  = __shfl(sv, jj);
            unsigned int pk = *(const unsigned int*)&xwg[(size_t)s * DFEAT + fo];
            acc0 += nm * bf2f(pk & 0xffffu);
            acc1 += nm * bf2f(pk >> 16);
        }
    }

    float2 b1 = *(const float2*)&bl[fo];
    float2 b2 = *(const float2*)&bg[fo];
    float2 a2 = *(const float2*)&A[base];
    float2 l2 = *(const float2*)&Lr[base];
    float v0 = acc0 + b1.x + b2.x;
    float v1 = acc1 + b1.y + b2.y;
    float w0 = 1.0f / (1.0f + __expf(-v0));
    float w1 = 1.0f / (1.0f + __expf(-v1));
    float o0 = 2.0f * (a2.x * w0 + l2.x * (1.0f - w0));
    float o1 = 2.0f * (a2.y * w1 + l2.y * (1.0f - w1));
    *(float2*)&out[base] = make_float2(o0, o1);
}

extern "C" void kernel_launch(void* const* d_in, const int* in_sizes, int n_in,
                              void* d_out, int out_size, void* d_ws, size_t ws_size,
                              hipStream_t stream)
{
    const float* activity = (const float*)d_in[0];
    const float* learning = (const float*)d_in[1];
    const int*   ei  = (const int*)d_in[2];
    const float* ew  = (const float*)d_in[3];
    const int*   gei = (const int*)d_in[4];
    const float* gew = (const float*)d_in[5];
    const float* Wl  = (const float*)d_in[6];
    const float* bl  = (const float*)d_in[7];
    const float* Wg  = (const float*)d_in[8];
    const float* bg  = (const float*)d_in[9];

    const int n  = in_sizes[0] / DFEAT;   // 50000
    const int El = in_sizes[3];           // 500000
    const int Eg = in_sizes[5];           // 600000
    const int n2 = 2 * n;
    const int E  = El + Eg;

    // ws layout (~36.3 MB):
    // [xwl bf16][xwg bf16][dc u64 2N][dinv f32 2N][ptr 2N][bsum 2048B][WT bf16 2*16K][edata int2 E]
    char* ws = (char*)d_ws;
    const size_t xwBytes = (size_t)n * DFEAT * 2;
    unsigned short* xwl = (unsigned short*)ws;
    unsigned short* xwg = (unsigned short*)(ws + xwBytes);
    unsigned long long* dc = (unsigned long long*)(ws + 2 * xwBytes);
    float* dinv = (float*)(ws + 2 * xwBytes + (size_t)n2 * 8);
    int*   ptr  = (int*)(ws + 2 * xwBytes + (size_t)n2 * 12);
    int*   bsum = (int*)(ws + 2 * xwBytes + (size_t)n2 * 16);
    unsigned short* WT = (unsigned short*)(ws + 2 * xwBytes + (size_t)n2 * 16 + 2048);
    int2* edata = (int2*)(ws + 2 * xwBytes + (size_t)n2 * 16 + 2048 + 2 * 128 * 128 * 2);

    const int scanBlocks = (n2 + 255) / 256;       // 391

    hipMemsetAsync(dc, 0, (size_t)n2 * 8, stream);

    hist_kernel<<<dim3(128 + (E + 255) / 256), dim3(256), 0, stream>>>(
        ei + El, ew, gei + Eg, gew, Wl, Wg, WT, dc, El, Eg, n);

    scan1_kernel<<<dim3(scanBlocks), dim3(256), 0, stream>>>(dc, ptr, bsum, dinv, n2);
    scan2_kernel<<<dim3(1), dim3(512), 0, stream>>>(bsum, scanBlocks);
    scan3_kernel<<<dim3(scanBlocks), dim3(256), 0, stream>>>(ptr, bsum, n2);

    pos_scatter_kernel<<<dim3((E + 255) / 256), dim3(256), 0, stream>>>(
        ei, ei + El, ew, gei, gei + Eg, gew, dinv, ptr, edata, El, Eg, n);

    gemm_kernel<<<dim3((n + 63) / 64), dim3(256), 0, stream>>>(
        activity, learning, WT, xwl, xwg, n);

    gather_kernel<<<dim3((n + 3) / 4), dim3(256), 0, stream>>>(
        xwl, xwg, ptr, edata, dinv, activity, learning, bl, bg, (float*)d_out, n);
}